// Round 8
// baseline (472.816 us; speedup 1.0000x reference)
//
#include <hip/hip_runtime.h>
#include <math.h>

#define B_ROWS 16384
#define D_DIM  2048
#define H_DIM  512

typedef __attribute__((ext_vector_type(8))) short  s16x8;  // 8 bf16
typedef __attribute__((ext_vector_type(4))) float  f32x4;  // MFMA acc

union U8 { unsigned short us[8]; s16x8 v; };
union U4 { unsigned short us[4]; short4 v; };

static __device__ __forceinline__ unsigned short f2bf(float f) {
    unsigned u = __float_as_uint(f);
    u += 0x7FFFu + ((u >> 16) & 1u);   // RNE (no NaN inputs here)
    return (unsigned short)(u >> 16);
}

// ---------------- Kernel 0: pack W1 -> bf16 hi/lo in MFMA B-fragment order ----------------
// Fragment layout (16x16x32): lane l holds B[k=(l>>4)*8+j][n=l&15], j=0..7.
// Wp[type][c=k>>5][Nt=n>>4][lane][j], 2 types x 64 c x 32 Nt x 64 lanes x 8 bf16 = 4 MB.
__global__ __launch_bounds__(256) void pack_w1(
    const float* __restrict__ W1, unsigned short* __restrict__ Wp)
{
    const int gid = blockIdx.x * 256 + threadIdx.x;   // 131072 = 256 k-octets x 512 n
    const int ko = gid >> 9;          // k-octet 0..255
    const int n  = gid & 511;
    U8 h8, l8;
    #pragma unroll
    for (int j = 0; j < 8; ++j) {
        const float w = W1[(size_t)(ko * 8 + j) * H_DIM + n];
        const unsigned short h = f2bf(w);
        const float hf = __uint_as_float((unsigned)h << 16);
        h8.us[j] = h;
        l8.us[j] = f2bf(w - hf);
    }
    const int c    = ko >> 2;
    const int lane = (n & 15) | ((ko & 3) << 4);
    const int Nt   = n >> 4;
    const size_t baseH = ((((size_t)0 * 64 + c) * 32 + Nt) * 64 + lane) * 8;
    const size_t baseL = ((((size_t)1 * 64 + c) * 32 + Nt) * 64 + lane) * 8;
    *(s16x8*)(Wp + baseH) = h8.v;
    *(s16x8*)(Wp + baseL) = l8.v;
}

// ---------------- Kernel 1: predictor GEMM via bf16 MFMA, 2-product split ----------------
// L2-traffic-first schedule: 128-row x 256-col blocks, 1024 thr (16 waves = 2 row-groups
// x 8 col-slices), grid (128,2) -> 1 block/CU, 16 waves/CU. The 2 row-group waves sharing
// a col-slice read IDENTICAL B addresses in the same barrier phase -> L1 dedupes -> per-CU
// L2 B-pull halves vs the 2-block config (1 GB -> 512 MB chip-wide). x staged with
// prefetch DEPTH 2: x(s+2) loaded at step top, x(s+1) converted+written at step bottom
// from regs loaded a full step earlier -> no vmcnt stall at the ds_write / barrier drain.
// Per-wave compute identical to round 7: K-step 64 (2 chunks), 32 MFMA/step, xh-only A
// with W hi/lo (xh.wh + xh.wl), bit-identical logits to round 7.
__global__ __launch_bounds__(1024, 4) void predictor_gemm(
    const float* __restrict__ x, const unsigned short* __restrict__ Wp,
    const float* __restrict__ b1, const float* __restrict__ W2,
    double* __restrict__ logit)
{
    // [buf][chunk][Mt(8)*512 + lane*8 + j]: 2 x 2 x 4096 shorts = 32 KB
    __shared__ __align__(16) unsigned short Abuf[2][2][4096];

    const int tid = threadIdx.x;
    const int l   = tid & 63;
    const int Nw  = tid >> 6;          // 0..15
    const int cs  = Nw & 7;            // col-slice 0..7
    const int rg  = Nw >> 3;           // row-group 0..1
    const int bx  = blockIdx.x;        // 0..127
    const int by  = blockIdx.y;        // column half
    const int rowBase = bx * 128;
    const int NtBase  = by * 16 + cs * 2;   // global col-tile index 0..31

    // staging role: thread -> (row sm 0..127, k-quad shh), 4 consecutive k-values/chunk
    const int sm  = tid >> 3;          // 0..127
    const int shh = tid & 7;           // 0..7
    const float* xp = x + (size_t)(rowBase + sm) * D_DIM + shh * 4;
    const int stIdx = (sm >> 4) * 512 + (((sm & 15) | ((shh >> 1) << 4)) << 3) + (shh & 1) * 4;

    const s16x8* WpV = (const s16x8*)Wp;
    const s16x8* bB = WpV + (size_t)NtBase * 64 + l;

    f32x4 acc[4][2];
    #pragma unroll
    for (int mt = 0; mt < 4; ++mt)
        #pragma unroll
        for (int nt = 0; nt < 2; ++nt)
            acc[mt][nt] = {0.f, 0.f, 0.f, 0.f};

    // prologue: stage step 0 (xh only, both chunks) into buf 0; preload step-1 x into
    // regs (depth-2 pipeline); preload chunk-0 B frags
    {
        const float4 v0 = *(const float4*)(xp);
        const float4 v1 = *(const float4*)(xp + 32);
        const float xv[8] = {v0.x, v0.y, v0.z, v0.w, v1.x, v1.y, v1.z, v1.w};
        U4 h4[2];
        #pragma unroll
        for (int ch = 0; ch < 2; ++ch)
            #pragma unroll
            for (int j = 0; j < 4; ++j)
                h4[ch].us[j] = f2bf(xv[ch * 4 + j]);
        *(short4*)&Abuf[0][0][stIdx] = h4[0].v;
        *(short4*)&Abuf[0][1][stIdx] = h4[1].v;
    }
    float4 xN0 = *(const float4*)(xp + 64);        // x for step 1, chunk a
    float4 xN1 = *(const float4*)(xp + 64 + 32);   // x for step 1, chunk b
    s16x8 BhA[2], BlA[2];
    #pragma unroll
    for (int nt = 0; nt < 2; ++nt) {
        BhA[nt] = bB[nt * 64];
        BlA[nt] = bB[131072 + nt * 64];
    }
    __syncthreads();

    for (int s = 0; s < 32; ++s) {
        const int cur = s & 1, nxt = cur ^ 1;
        const int cb = 2 * s + 1;

        // issue x loads for step s+2 (consumed at bottom of step s+1)
        float4 xF0, xF1;
        if (s < 30) {
            xF0 = *(const float4*)(xp + (s + 2) * 64);
            xF1 = *(const float4*)(xp + (s + 2) * 64 + 32);
        }
        // issue chunk-b B loads (consumed after chunk-a MFMAs)
        s16x8 BhB[2], BlB[2];
        #pragma unroll
        for (int nt = 0; nt < 2; ++nt) {
            BhB[nt] = bB[(size_t)cb * 2048 + nt * 64];
            BlB[nt] = bB[131072 + (size_t)cb * 2048 + nt * 64];
        }

        // ---- chunk a ----
        s16x8 Ah[4];
        #pragma unroll
        for (int mt = 0; mt < 4; ++mt)
            Ah[mt] = *(const s16x8*)&Abuf[cur][0][(rg * 4 + mt) * 512 + l * 8];
        #pragma unroll
        for (int mt = 0; mt < 4; ++mt)
            #pragma unroll
            for (int nt = 0; nt < 2; ++nt) {
                acc[mt][nt] = __builtin_amdgcn_mfma_f32_16x16x32_bf16(Ah[mt], BhA[nt], acc[mt][nt], 0, 0, 0);
                acc[mt][nt] = __builtin_amdgcn_mfma_f32_16x16x32_bf16(Ah[mt], BlA[nt], acc[mt][nt], 0, 0, 0);
            }

        // prefetch next step's chunk-a B
        if (s < 31) {
            #pragma unroll
            for (int nt = 0; nt < 2; ++nt) {
                BhA[nt] = bB[(size_t)(cb + 1) * 2048 + nt * 64];
                BlA[nt] = bB[131072 + (size_t)(cb + 1) * 2048 + nt * 64];
            }
        }

        // ---- chunk b ----
        #pragma unroll
        for (int mt = 0; mt < 4; ++mt)
            Ah[mt] = *(const s16x8*)&Abuf[cur][1][(rg * 4 + mt) * 512 + l * 8];
        #pragma unroll
        for (int mt = 0; mt < 4; ++mt)
            #pragma unroll
            for (int nt = 0; nt < 2; ++nt) {
                acc[mt][nt] = __builtin_amdgcn_mfma_f32_16x16x32_bf16(Ah[mt], BhB[nt], acc[mt][nt], 0, 0, 0);
                acc[mt][nt] = __builtin_amdgcn_mfma_f32_16x16x32_bf16(Ah[mt], BlB[nt], acc[mt][nt], 0, 0, 0);
            }

        // stage step s+1 from regs loaded a full step ago (no vmcnt stall here)
        if (s < 31) {
            const float xv[8] = {xN0.x, xN0.y, xN0.z, xN0.w, xN1.x, xN1.y, xN1.z, xN1.w};
            U4 h4[2];
            #pragma unroll
            for (int ch = 0; ch < 2; ++ch)
                #pragma unroll
                for (int j = 0; j < 4; ++j)
                    h4[ch].us[j] = f2bf(xv[ch * 4 + j]);
            *(short4*)&Abuf[nxt][0][stIdx] = h4[0].v;
            *(short4*)&Abuf[nxt][1][stIdx] = h4[1].v;
            xN0 = xF0;
            xN1 = xF1;
        }
        __syncthreads();
    }

    // epilogue: +b1, relu, fp64 dot with W2, cross-lane reduce, atomic
    float  b1v[2];
    double w2v[2];
    #pragma unroll
    for (int nt = 0; nt < 2; ++nt) {
        const int j = (NtBase + nt) * 16 + (l & 15);
        b1v[nt] = b1[j];
        w2v[nt] = (double)W2[j];
    }
    #pragma unroll
    for (int mt = 0; mt < 4; ++mt)
        #pragma unroll
        for (int reg = 0; reg < 4; ++reg) {
            double p = 0.0;
            #pragma unroll
            for (int nt = 0; nt < 2; ++nt) {
                const float h = acc[mt][nt][reg] + b1v[nt];
                if (h > 0.0f) p = fma((double)h, w2v[nt], p);
            }
            #pragma unroll
            for (int m2 = 1; m2 < 16; m2 <<= 1) p += __shfl_xor(p, m2, 64);
            if ((l & 15) == 0)
                atomicAdd(&logit[rowBase + rg * 64 + mt * 16 + (l >> 4) * 4 + reg], p);
        }
}

// ------------- Kernel 2: wave-per-row radix select + writeback (barrier-free) -------------
// One wave owns one row. Pass-0 fast path: exact popc counts of {|x|<0.5} and {0.5<=|x|<2}
// replace the (measured, 2.2e7-conflict) hot-bin LDS histogram; exact LDS fallback kept.
__global__ __launch_bounds__(256) void select_and_write(
    const float* __restrict__ x, const float* __restrict__ b2,
    const double* __restrict__ logit,
    float* __restrict__ out_sparse, float* __restrict__ out_mask,
    float* __restrict__ out_sparsity, float* __restrict__ out_actual,
    double* __restrict__ l1rows)
{
    __shared__ int hist[4][1024];    // per wave: 256 bins x 4 sub-counters

    const int tid = threadIdx.x;
    const int w = tid >> 6, l = tid & 63;
    const int row = blockIdx.x * 4 + w;
    int* hw = hist[w];

    const float4* x4 = (const float4*)(x + (size_t)row * D_DIM);
    float4 vv[8];
    #pragma unroll
    for (int i = 0; i < 8; ++i) vv[i] = x4[i * 64 + l];   // elems (i*64+l)*4..+3

    // k from logit (all lanes compute identically; wave-uniform)
    const double L = logit[row] + (double)b2[0];
    const double sig = 1.0 / (1.0 + exp(-L));
    const double s = 0.05 + 0.25 * sig;                 // MIN_S + (MAX_S-MIN_S)*sig
    int k = (int)rint(2048.0 * (1.0 - s));              // half-even == np.round
    if (k < 1) k = 1;
    if (k > 2048) k = 2048;
    if (l == 0) out_sparsity[row] = (float)s;

    // ---- pass-0 fast path: exact counts of |x| < 0.5 and 0.5 <= |x| < 2.0 ----
    int below = 0, inbin = 0;
    #pragma unroll
    for (int i = 0; i < 8; ++i) {
        const float qq[4] = {vv[i].x, vv[i].y, vv[i].z, vv[i].w};
        #pragma unroll
        for (int c = 0; c < 4; ++c) {
            const unsigned ub = __float_as_uint(qq[c]) & 0x7FFFFFFFu;
            below += (ub < 0x3F000000u) ? 1 : 0;
            inbin += (ub >= 0x3F000000u && ub < 0x40000000u) ? 1 : 0;
        }
    }
    {
        int packed = below | (inbin << 16);
        #pragma unroll
        for (int m2 = 1; m2 < 64; m2 <<= 1) packed += __shfl_xor(packed, m2);
        below = packed & 0xFFFF;
        inbin = packed >> 16;
    }

    int krem;
    unsigned prefix;
    bool fast0;
    if (k > below && k <= below + inbin) {   // wave-uniform
        fast0 = true;
        prefix = 0x3F000000u;
        krem = k - below;
    } else {
        fast0 = false;
        prefix = 0;
        krem = k;
    }

    #pragma unroll
    for (int pass = 0; pass < 4; ++pass) {
        if (pass == 0 && fast0) continue;    // wave-uniform skip
        const int shift = 24 - pass * 8;
        const unsigned pmask = (pass == 0) ? 0u : (0xFFFFFFFFu << (shift + 8));

        #pragma unroll
        for (int j = 0; j < 4; ++j)
            ((int4*)hw)[l + 64 * j] = int4{0, 0, 0, 0};
        __builtin_amdgcn_wave_barrier();
        __threadfence_block();   // lgkmcnt drain; wave-synchronous, no s_barrier

        #pragma unroll
        for (int i = 0; i < 8; ++i) {
            const float qq[4] = {vv[i].x, vv[i].y, vv[i].z, vv[i].w};
            #pragma unroll
            for (int c = 0; c < 4; ++c) {
                const unsigned ub = __float_as_uint(qq[c]) & 0x7FFFFFFFu;
                if (pass == 0 || (ub & pmask) == prefix)
                    atomicAdd(&hw[((ub >> shift) & 255) * 4 + (l & 3)], 1);
            }
        }
        __builtin_amdgcn_wave_barrier();
        __threadfence_block();

        // scan: lane l owns bins 4l..4l+3 (each bin = one int4 of sub-counters)
        int b_[4], tot = 0;
        #pragma unroll
        for (int j = 0; j < 4; ++j) {
            const int4 c4 = ((const int4*)hw)[4 * l + j];
            b_[j] = c4.x + c4.y + c4.z + c4.w;
            tot += b_[j];
        }
        int sc = tot;
        #pragma unroll
        for (int off = 1; off < 64; off <<= 1) {
            const int n = __shfl_up(sc, off);
            if (l >= off) sc += n;
        }
        int cum = sc - tot;           // elems in bins < 4l
        int found = 0;
        #pragma unroll
        for (int j = 0; j < 4; ++j) {
            if (krem > cum && krem <= cum + b_[j])
                found = ((4 * l + j) << 12) | (krem - cum);   // one lane-j only
            cum += b_[j];
        }
        #pragma unroll
        for (int m2 = 1; m2 < 64; m2 <<= 1) found |= __shfl_xor(found, m2);
        prefix |= ((unsigned)(found >> 12)) << shift;
        krem = found & 0xFFF;
    }
    const unsigned thr = prefix;   // exact bit pattern of k-th smallest |x|

    // writeback: mask = (|x| > thr), bitwise-identical to reference compare
    float4* os4 = (float4*)(out_sparse + (size_t)row * D_DIM);
    float4* om4 = (float4*)(out_mask   + (size_t)row * D_DIM);
    int cnt = 0;
    double lp = 0.0;
    #pragma unroll
    for (int i = 0; i < 8; ++i) {
        const float qq[4] = {vv[i].x, vv[i].y, vv[i].z, vv[i].w};
        float sq[4], mq[4];
        #pragma unroll
        for (int c = 0; c < 4; ++c) {
            const unsigned ub = __float_as_uint(qq[c]) & 0x7FFFFFFFu;
            const bool keep = (ub > thr);
            mq[c] = keep ? 1.0f : 0.0f;
            sq[c] = keep ? qq[c] : 0.0f;
            cnt += keep ? 1 : 0;
            if (keep) lp += (double)fabsf(qq[c]);
        }
        os4[i * 64 + l] = float4{sq[0], sq[1], sq[2], sq[3]};
        om4[i * 64 + l] = float4{mq[0], mq[1], mq[2], mq[3]};
    }
    #pragma unroll
    for (int m2 = 1; m2 < 64; m2 <<= 1) {
        lp  += __shfl_xor(lp, m2);
        cnt += __shfl_xor(cnt, m2);
    }
    if (l == 0) {
        l1rows[row] = lp;
        out_actual[row] = (float)cnt * (1.0f / 2048.0f);
    }
}

// ---------------- Kernel 3: reduce row L1 sums -> l1_reg (widened to 1024 thr) -----------
__global__ __launch_bounds__(1024) void finalize_l1(
    const double* __restrict__ l1rows, float* __restrict__ out_l1)
{
    __shared__ double sh[1024];
    double s = 0.0;
    for (int i = threadIdx.x; i < B_ROWS; i += 1024) s += l1rows[i];
    sh[threadIdx.x] = s;
    __syncthreads();
    for (int st = 512; st > 0; st >>= 1) {
        if (threadIdx.x < st) sh[threadIdx.x] += sh[threadIdx.x + st];
        __syncthreads();
    }
    if (threadIdx.x == 0) out_l1[0] = (float)(sh[0] / (double)B_ROWS);
}

extern "C" void kernel_launch(void* const* d_in, const int* in_sizes, int n_in,
                              void* d_out, int out_size, void* d_ws, size_t ws_size,
                              hipStream_t stream) {
    const float* x  = (const float*)d_in[0];
    const float* W1 = (const float*)d_in[1];
    const float* b1 = (const float*)d_in[2];
    const float* W2 = (const float*)d_in[3];
    const float* b2 = (const float*)d_in[4];

    float* out = (float*)d_out;
    float* out_sparse   = out;                                   // B*D
    float* out_mask     = out + (size_t)B_ROWS * D_DIM;          // B*D
    float* out_sparsity = out + 2ull * B_ROWS * D_DIM;           // B
    float* out_actual   = out_sparsity + B_ROWS;                 // B
    float* out_l1       = out_actual + B_ROWS;                   // 1

    double* logit  = (double*)d_ws;                        // B doubles (atomics)
    double* l1rows = logit + B_ROWS;                       // B doubles
    unsigned short* Wp = (unsigned short*)(l1rows + B_ROWS);  // 4 MB packed W1 hi/lo

    hipMemsetAsync(d_ws, 0, (size_t)B_ROWS * sizeof(double), stream);

    pack_w1<<<512, 256, 0, stream>>>(W1, Wp);
    dim3 g1(B_ROWS / 128, 2);
    predictor_gemm<<<g1, 1024, 0, stream>>>(x, Wp, b1, W2, logit);
    select_and_write<<<B_ROWS / 4, 256, 0, stream>>>(x, b2, logit, out_sparse, out_mask,
                                                     out_sparsity, out_actual, l1rows);
    finalize_l1<<<1, 1024, 0, stream>>>(l1rows, out_l1);
}